// Round 22
// baseline (105.197 us; speedup 1.0000x reference)
//
#include <hip/hip_runtime.h>

typedef unsigned int u32;
typedef unsigned short u16;
typedef int i32x4 __attribute__((ext_vector_type(4)));
typedef int i32x16 __attribute__((ext_vector_type(16)));

// ws layout (bytes):
//   [0..3]      amax (float)
//   [64..1087]  256 partial maxima (float)
//   [2048..]    Wq2: fragment-major i8 weights, 768 KB:
//               addr = nt*24576 + ks*1024 + col*32 + kb
//               (n = nt*32+col in [0,1024), k = ks*32+kb in [0,768))
#define WQ_OFF 2048

__device__ __forceinline__ void gld16(const void* g, void* l) {
    __builtin_amdgcn_global_load_lds(
        (const __attribute__((address_space(1))) void*)g,
        (__attribute__((address_space(3))) void*)l, 16, 0, 0);
}

// ---------------------------------------------------------------------------
// absmax two-stage tree (no atomics)
// ---------------------------------------------------------------------------
__global__ __launch_bounds__(256) void amax_stage1(const float* __restrict__ W,
                                                   float* __restrict__ part) {
    int t = blockIdx.x * 256 + threadIdx.x;
    float v = 0.0f;
#pragma unroll
    for (int k = 0; k < 12; ++k) v = fmaxf(v, fabsf(W[t + (k << 16)]));
#pragma unroll
    for (int d = 32; d >= 1; d >>= 1) v = fmaxf(v, __shfl_xor(v, d));
    __shared__ float sm[4];
    if ((threadIdx.x & 63) == 0) sm[threadIdx.x >> 6] = v;
    __syncthreads();
    if (threadIdx.x == 0)
        part[blockIdx.x] = fmaxf(fmaxf(sm[0], sm[1]), fmaxf(sm[2], sm[3]));
}

__global__ __launch_bounds__(256) void amax_stage2(const float* __restrict__ part,
                                                   float* __restrict__ amax) {
    float v = part[threadIdx.x];
#pragma unroll
    for (int d = 32; d >= 1; d >>= 1) v = fmaxf(v, __shfl_xor(v, d));
    __shared__ float sm[4];
    if ((threadIdx.x & 63) == 0) sm[threadIdx.x >> 6] = v;
    __syncthreads();
    if (threadIdx.x == 0)
        amax[0] = fmaxf(fmaxf(sm[0], sm[1]), fmaxf(sm[2], sm[3]));
}

// ---------------------------------------------------------------------------
// quantize W_in [1024][768] f32 -> Wq2 fragment-major i8 (validated r9-r21)
// ---------------------------------------------------------------------------
__global__ __launch_bounds__(192) void quant_k(const float* __restrict__ W,
                                               const float* __restrict__ amax,
                                               u32* __restrict__ Wq4) {
    const int n = blockIdx.x, kd = threadIdx.x;     // kd: dword index 0..191
    float s = 127.0f / amax[0];
    float4 v = ((const float4*)(W + n * 768))[kd];
    int a0 = (int)rintf(v.x * s), a1 = (int)rintf(v.y * s);
    int a2 = (int)rintf(v.z * s), a3 = (int)rintf(v.w * s);
    u32 wq = (u32)(a0 & 0xFF) | ((u32)(a1 & 0xFF) << 8) |
             ((u32)(a2 & 0xFF) << 16) | ((u32)(a3 & 0xFF) << 24);
    const int nt = n >> 5, c = n & 31, kc = kd >> 3, kb4 = kd & 7;
    Wq4[nt * 6144 + kc * 256 + c * 8 + kb4] = wq;
}

// ---------------------------------------------------------------------------
// Fused forward — r19 champion with the main loop rebuilt as a 3-buffer,
// 2-deep COUNTED-vmcnt pipeline (T3+T4 done properly):
//   window = 12 KB (chunk c, kc-quarter q): 12 slabs of 1 KB, 3 staged/wave.
//   Per window: s_waitcnt vmcnt(3) [batch w done, batch w+1 stays IN FLIGHT
//   across the barrier — never drains to 0 in-loop] -> raw s_barrier ->
//   sched_barrier(0) -> STAGE(w+2 into buf[(w+2)%3]) -> 12 MFMA.
//   WAR safe: STAGE(w+2) is after barrier(w), which post-dates all reads of
//   that buffer (window w-1). Sub-windows macro-expanded with literal q so
//   afr[] indexing stays compile-time (rule #20).
// Everything else r19-verbatim: coalesced A-phase, hoisted afr[24],
// fused epilogue, grid 512 -> 2 blocks/CU, (2,2) 256-reg budget.
// ---------------------------------------------------------------------------
__global__ __launch_bounds__(256)
__attribute__((amdgpu_waves_per_eu(2, 2)))
void nnue_fwd(
    const float* __restrict__ x,       // [B][768], values in {0,1}
    const signed char* __restrict__ Wq2,
    const float* __restrict__ amax,
    const float* __restrict__ b_in,    // [1024]
    const float* __restrict__ W_h,     // [8][1024]
    const float* __restrict__ b_h,     // [8]
    const float* __restrict__ W_psqt,  // [768]
    float* __restrict__ out) {         // [B]

    __shared__ __align__(16) signed char bufs[3][12288];  // 36 KB
    __shared__ __align__(16) u16 abits16[128][2][24];     // 12 KB
    __shared__ int   bmeta[128];
    __shared__ float pmeta[128];

    const int t = threadIdx.x;
    const int l = t & 63, w = t >> 6;   // 4 waves = 4 row-strips
    const int cl = l & 31;              // row-in-strip / col-in-tile
    const int hi = l >> 5;              // K-half-of-fragment selector
    const size_t row0 = (size_t)blockIdx.x << 7;

    // STAGE(dst, c_, q_): window = chunk c_, kc-quarter q_ (kc q_*6..q_*6+5),
    // both n-tiles. 12 slabs of 1 KB; wave w stages slabs jj = w*3..w*3+2.
#define STAGE(dst, c_, q_)                                                  \
    _Pragma("unroll")                                                       \
    for (int i = 0; i < 3; ++i) {                                           \
        int jj  = w * 3 + i;                /* 0..11 */                     \
        int ntl = jj >= 6 ? 1 : 0;                                          \
        int kcl = jj - ntl * 6;                                             \
        gld16(Wq2 + (size_t)(((c_) << 1) + ntl) * 24576                     \
                  + (size_t)((q_) * 6 + kcl) * 1024 + (l << 4),             \
              (signed char*)(dst) + jj * 1024);                             \
    }

    STAGE(bufs[0], 0, 0)        // windows 0 and 1 in flight under A-phase
    STAGE(bufs[1], 0, 1)

    // ---- A phase (coalesced): wave processes its 32 rows sequentially ---
    {
        const float4* pw = (const float4*)W_psqt;
#pragma unroll 2
        for (int rr = 0; rr < 32; ++rr) {
            const int row = (w << 5) + rr;
            const float4* xr = (const float4*)(x + (row0 + row) * 768);
            float ps = 0.0f;
            int cnt = 0;
            u32 mym[3];
#pragma unroll
            for (int i = 0; i < 3; ++i) {
                float4 f = xr[i * 64 + l];          // coalesced 1 KB / wave
                float4 p = pw[i * 64 + l];
                u32 nib = (__float_as_uint(f.x) >> 29)
                        | ((__float_as_uint(f.y) >> 29) << 1)
                        | ((__float_as_uint(f.z) >> 29) << 2)
                        | ((__float_as_uint(f.w) >> 29) << 3);
                ps = fmaf(f.x, p.x, ps); ps = fmaf(f.y, p.y, ps);
                ps = fmaf(f.z, p.z, ps); ps = fmaf(f.w, p.w, ps);
                cnt += __popc(nib);
                u32 v = nib << ((l & 3) << 2);
                v |= __shfl_xor(v, 1);
                v |= __shfl_xor(v, 2);              // 4 lanes -> m16
                mym[i] = v;
            }
            if ((l & 3) == 0) {
#pragma unroll
                for (int i = 0; i < 3; ++i) {
                    int q = (i << 4) + (l >> 2);    // 16-k chunk 0..47
                    abits16[row][q & 1][q >> 1] = (u16)mym[i];
                }
            }
#pragma unroll
            for (int d = 1; d < 64; d <<= 1) {
                ps  += __shfl_xor(ps, d);
                cnt += __shfl_xor(cnt, d);
            }
            if (l == 0) {
                bmeta[row] = (cnt - 1) >> 2;
                pmeta[row] = ps;
            }
        }
    }
    __syncthreads();            // panel+meta visible; windows 0,1 landed

    // ---- per-lane setup: gather Ab, expand ALL 24 fragments ONCE --------
    const int r = (w << 5) + cl;
    i32x4 afr[24];              // 96 VGPRs, live across the whole main loop
    {
        const uint4* ap = (const uint4*)&abits16[r][hi][0];
        uint4 A0 = ap[0], A1 = ap[1], A2 = ap[2];
        u32 Ab[12] = {A0.x, A0.y, A0.z, A0.w,
                      A1.x, A1.y, A1.z, A1.w,
                      A2.x, A2.y, A2.z, A2.w};
#pragma unroll
        for (int ks = 0; ks < 24; ++ks) {
            u32 pair = Ab[ks >> 1];
            u32 m = (ks & 1) ? (pair >> 16) : (pair & 0xFFFFu);
            afr[ks][0] = (int)(((m         & 0xFu) * 0x00204081u) & 0x01010101u);
            afr[ks][1] = (int)((((m >> 4)  & 0xFu) * 0x00204081u) & 0x01010101u);
            afr[ks][2] = (int)((((m >> 8)  & 0xFu) * 0x00204081u) & 0x01010101u);
            afr[ks][3] = (int)((((m >> 12)       ) * 0x00204081u) & 0x01010101u);
        }
    }

    int whoff[16];
#pragma unroll
    for (int g = 0; g < 16; ++g) {
        int er = (w << 5) + (g & 3) + ((g >> 2) << 3) + (hi << 2);
        whoff[g] = bmeta[er] << 10;             // bucket * 1024
    }

    const float sc = amax[0] * (1.0f / 127.0f);
    float rs[16];
#pragma unroll
    for (int g = 0; g < 16; ++g) rs[g] = 0.0f;

    const i32x16 zacc = {0,0,0,0,0,0,0,0,0,0,0,0,0,0,0,0};

    // ---- main loop: 64 windows, 3 buffers, counted vmcnt -----------------
    // SUBWIN(q_): window w64 = 4c + q_ (q_ literal -> afr index static).
    //   wait: vmcnt(3) except the very last window (vmcnt(0)).
    //   stage: window w64+2 -> buf (bw+2)%3, content (c2, q2) computed from
    //   literal q_; skipped for the last two windows.
#define SUBWIN(q_)                                                          \
    {                                                                       \
        if ((q_) < 3 || c < 15)                                             \
            asm volatile("s_waitcnt vmcnt(3)" ::: "memory");                \
        else                                                                \
            asm volatile("s_waitcnt vmcnt(0)" ::: "memory");                \
        __builtin_amdgcn_s_barrier();                                       \
        __builtin_amdgcn_sched_barrier(0);                                  \
        if ((q_) < 2 || c < 15) {                                           \
            int b2 = bw + 2; if (b2 >= 3) b2 -= 3;                          \
            const int c2 = c + ((q_) >= 2 ? 1 : 0);                         \
            STAGE(bufs[b2], c2, (((q_) + 2) & 3))                           \
        }                                                                   \
        {                                                                   \
            const signed char* bb = bufs[bw] + (cl << 5) + (hi << 4);       \
            _Pragma("unroll")                                               \
            for (int kcl = 0; kcl < 6; ++kcl) {                             \
                const int ks = (q_) * 6 + kcl;                              \
                i32x4 b0 = *(const i32x4*)(bb + (kcl << 10));               \
                i32x4 b1 = *(const i32x4*)(bb + 6144 + (kcl << 10));        \
                acc0 = __builtin_amdgcn_mfma_i32_32x32x32_i8(afr[ks], b0, acc0, 0, 0, 0); \
                acc1 = __builtin_amdgcn_mfma_i32_32x32x32_i8(afr[ks], b1, acc1, 0, 0, 0); \
            }                                                               \
        }                                                                   \
        bw = (bw == 2) ? 0 : bw + 1;                                        \
    }

    int bw = 0;                 // buffer index of the current window
    for (int c = 0; c < 16; ++c) {
        i32x16 acc0 = zacc, acc1 = zacc;
        SUBWIN(0)
        SUBWIN(1)
        SUBWIN(2)
        SUBWIN(3)

        // fused epilogue for chunk c (regs + L1-hot globals)
        const int col0 = (c << 6) + cl;
        const float bi0 = b_in[col0], bi1 = b_in[col0 + 32];
#pragma unroll
        for (int g = 0; g < 16; ++g) {
            float h0 = fminf(fmaxf(fmaf((float)acc0[g], sc, bi0), 0.f), 1.f);
            float h1 = fminf(fmaxf(fmaf((float)acc1[g], sc, bi1), 0.f), 1.f);
            rs[g] = fmaf(h0, W_h[whoff[g] + col0], rs[g]);
            rs[g] = fmaf(h1, W_h[whoff[g] + col0 + 32], rs[g]);
        }
    }
#undef SUBWIN
#undef STAGE

    // ---- reduce over 32 col-lanes, write --------------------------------
#pragma unroll
    for (int g = 0; g < 16; ++g) {
#pragma unroll
        for (int d = 1; d < 32; d <<= 1) rs[g] += __shfl_xor(rs[g], d);
    }
    if (cl == 0) {
#pragma unroll
        for (int g = 0; g < 16; ++g) {
            int er = (w << 5) + (g & 3) + ((g >> 2) << 3) + (hi << 2);
            out[row0 + er] = rs[g] + pmeta[er] + b_h[whoff[g] >> 10];
        }
    }
}

extern "C" void kernel_launch(void* const* d_in, const int* in_sizes, int n_in,
                              void* d_out, int out_size, void* d_ws, size_t ws_size,
                              hipStream_t stream) {
    const float* x      = (const float*)d_in[0];
    const float* W_in   = (const float*)d_in[1];
    const float* b_in   = (const float*)d_in[2];
    const float* W_h    = (const float*)d_in[3];
    const float* b_h    = (const float*)d_in[4];
    const float* W_psqt = (const float*)d_in[5];
    float* out = (float*)d_out;

    float* amax = (float*)d_ws;
    float* part = (float*)((char*)d_ws + 64);
    signed char* Wq2 = (signed char*)d_ws + WQ_OFF;     // 768 KB

    amax_stage1<<<256, 256, 0, stream>>>(W_in, part);
    amax_stage2<<<1, 256, 0, stream>>>(part, amax);
    quant_k<<<1024, 192, 0, stream>>>(W_in, amax, (u32*)Wq2);

    int B = out_size;                   // 65536
    nnue_fwd<<<B / 128, 256, 0, stream>>>(x, Wq2, amax, b_in, W_h, b_h,
                                          W_psqt, out);
}

// Round 23
// 99.719 us; speedup vs baseline: 1.0549x; 1.0549x over previous
//
#include <hip/hip_runtime.h>

typedef unsigned int u32;
typedef unsigned short u16;
typedef int i32x4 __attribute__((ext_vector_type(4)));
typedef int i32x16 __attribute__((ext_vector_type(16)));

// ws layout (bytes):
//   [0..3]      amax (float)
//   [64..1087]  256 partial maxima (float)
//   [2048..]    Wq2: fragment-major i8 weights, 768 KB:
//               addr = nt*24576 + ks*1024 + col*32 + kb
//               (n = nt*32+col in [0,1024), k = ks*32+kb in [0,768))
#define WQ_OFF 2048

__device__ __forceinline__ void gld16(const void* g, void* l) {
    __builtin_amdgcn_global_load_lds(
        (const __attribute__((address_space(1))) void*)g,
        (__attribute__((address_space(3))) void*)l, 16, 0, 0);
}

// ---------------------------------------------------------------------------
// absmax two-stage tree (no atomics)
// ---------------------------------------------------------------------------
__global__ __launch_bounds__(256) void amax_stage1(const float* __restrict__ W,
                                                   float* __restrict__ part) {
    int t = blockIdx.x * 256 + threadIdx.x;
    float v = 0.0f;
#pragma unroll
    for (int k = 0; k < 12; ++k) v = fmaxf(v, fabsf(W[t + (k << 16)]));
#pragma unroll
    for (int d = 32; d >= 1; d >>= 1) v = fmaxf(v, __shfl_xor(v, d));
    __shared__ float sm[4];
    if ((threadIdx.x & 63) == 0) sm[threadIdx.x >> 6] = v;
    __syncthreads();
    if (threadIdx.x == 0)
        part[blockIdx.x] = fmaxf(fmaxf(sm[0], sm[1]), fmaxf(sm[2], sm[3]));
}

__global__ __launch_bounds__(256) void amax_stage2(const float* __restrict__ part,
                                                   float* __restrict__ amax) {
    float v = part[threadIdx.x];
#pragma unroll
    for (int d = 32; d >= 1; d >>= 1) v = fmaxf(v, __shfl_xor(v, d));
    __shared__ float sm[4];
    if ((threadIdx.x & 63) == 0) sm[threadIdx.x >> 6] = v;
    __syncthreads();
    if (threadIdx.x == 0)
        amax[0] = fmaxf(fmaxf(sm[0], sm[1]), fmaxf(sm[2], sm[3]));
}

// ---------------------------------------------------------------------------
// quantize W_in [1024][768] f32 -> Wq2 fragment-major i8 (validated r9-r22)
// ---------------------------------------------------------------------------
__global__ __launch_bounds__(192) void quant_k(const float* __restrict__ W,
                                               const float* __restrict__ amax,
                                               u32* __restrict__ Wq4) {
    const int n = blockIdx.x, kd = threadIdx.x;     // kd: dword index 0..191
    float s = 127.0f / amax[0];
    float4 v = ((const float4*)(W + n * 768))[kd];
    int a0 = (int)rintf(v.x * s), a1 = (int)rintf(v.y * s);
    int a2 = (int)rintf(v.z * s), a3 = (int)rintf(v.w * s);
    u32 wq = (u32)(a0 & 0xFF) | ((u32)(a1 & 0xFF) << 8) |
             ((u32)(a2 & 0xFF) << 16) | ((u32)(a3 & 0xFF) << 24);
    const int nt = n >> 5, c = n & 31, kc = kd >> 3, kb4 = kd & 7;
    Wq4[nt * 6144 + kc * 256 + c * 8 + kb4] = wq;
}

// ---------------------------------------------------------------------------
// Fused forward — FINAL CHAMPION (r19, bench 99.5/99.8 us across runs):
// r12's 2-phase pipelined schedule + coalesced A-phase (r18) + hoisted
// af-expansion (r19). At the (2,2) shell's 256-reg unified budget, all 24
// expanded A-fragments (96 VGPRs) fit alongside acc/rs/whoff, so the
// bit->i8 expansion runs ONCE per lane. COMPUTE is pure ds_read + MFMA.
// 2-phase pipelined 24 KB windows, stage-before-compute, 2 barriers/chunk,
// grid 512 -> 2 blocks/CU.
// Plateau note (r8-r22): ~100 us bench is the structural minimum for this
// kernel class in HIP source. Bracketed by: occupancy 22->43% (r13-r15),
// zero-barrier private staging (r16), counted-vmcnt 2-deep 3-buffer (r22),
// VALU hoist (r19: -10pp VALUBusy, 0 us), coalescing (r18), N-split (r20),
// kernel split (r17). All pipes idle at ~14% — latency/sync-bound, not a
// pipe roofline; the remaining gap needs hand-asm interleave (§5 caveat).
// ---------------------------------------------------------------------------
__global__ __launch_bounds__(256)
__attribute__((amdgpu_waves_per_eu(2, 2)))
void nnue_fwd(
    const float* __restrict__ x,       // [B][768], values in {0,1}
    const signed char* __restrict__ Wq2,
    const float* __restrict__ amax,
    const float* __restrict__ b_in,    // [1024]
    const float* __restrict__ W_h,     // [8][1024]
    const float* __restrict__ b_h,     // [8]
    const float* __restrict__ W_psqt,  // [768]
    float* __restrict__ out) {         // [B]

    __shared__ __align__(16) signed char bufs[2][24576];  // 48 KB
    __shared__ __align__(16) u16 abits16[128][2][24];     // 12 KB
    __shared__ int   bmeta[128];
    __shared__ float pmeta[128];

    const int t = threadIdx.x;
    const int l = t & 63, w = t >> 6;   // 4 waves = 4 row-strips
    const int cl = l & 31;              // row-in-strip / col-in-tile
    const int hi = l >> 5;              // K-half-of-fragment selector
    const size_t row0 = (size_t)blockIdx.x << 7;

    // STAGE(dst, c_, h_): copy chunk c_ (64 cols), K-half h_ (384 k) -> dst.
#define STAGE(dst, c_, h_)                                                  \
    _Pragma("unroll")                                                       \
    for (int i = 0; i < 6; ++i) {                                           \
        int jj = w * 6 + i;                 /* 0..23 */                     \
        int ntl = jj >= 12 ? 1 : 0;                                         \
        int kcl = jj - ntl * 12;                                            \
        gld16(Wq2 + (size_t)(((c_) << 1) + ntl) * 24576                     \
                  + (size_t)((h_) * 12 + kcl) * 1024 + (l << 4),            \
              (signed char*)(dst) + jj * 1024);                             \
    }

    STAGE(bufs[0], 0, 0)        // stage 0 in flight under the A-phase

    // ---- A phase (coalesced): wave processes its 32 rows sequentially ---
    {
        const float4* pw = (const float4*)W_psqt;
#pragma unroll 2
        for (int rr = 0; rr < 32; ++rr) {
            const int row = (w << 5) + rr;
            const float4* xr = (const float4*)(x + (row0 + row) * 768);
            float ps = 0.0f;
            int cnt = 0;
            u32 mym[3];
#pragma unroll
            for (int i = 0; i < 3; ++i) {
                float4 f = xr[i * 64 + l];          // coalesced 1 KB / wave
                float4 p = pw[i * 64 + l];
                u32 nib = (__float_as_uint(f.x) >> 29)
                        | ((__float_as_uint(f.y) >> 29) << 1)
                        | ((__float_as_uint(f.z) >> 29) << 2)
                        | ((__float_as_uint(f.w) >> 29) << 3);
                ps = fmaf(f.x, p.x, ps); ps = fmaf(f.y, p.y, ps);
                ps = fmaf(f.z, p.z, ps); ps = fmaf(f.w, p.w, ps);
                cnt += __popc(nib);
                u32 v = nib << ((l & 3) << 2);
                v |= __shfl_xor(v, 1);
                v |= __shfl_xor(v, 2);              // 4 lanes -> m16
                mym[i] = v;
            }
            if ((l & 3) == 0) {
#pragma unroll
                for (int i = 0; i < 3; ++i) {
                    int q = (i << 4) + (l >> 2);    // 16-k chunk 0..47
                    abits16[row][q & 1][q >> 1] = (u16)mym[i];
                }
            }
#pragma unroll
            for (int d = 1; d < 64; d <<= 1) {
                ps  += __shfl_xor(ps, d);
                cnt += __shfl_xor(cnt, d);
            }
            if (l == 0) {
                bmeta[row] = (cnt - 1) >> 2;
                pmeta[row] = ps;
            }
        }
    }
    __syncthreads();            // panel+meta visible; stage 0 landed

    // ---- per-lane setup: gather Ab, expand ALL 24 fragments ONCE --------
    const int r = (w << 5) + cl;
    i32x4 afr[24];              // 96 VGPRs, live across the whole main loop
    {
        const uint4* ap = (const uint4*)&abits16[r][hi][0];
        uint4 A0 = ap[0], A1 = ap[1], A2 = ap[2];
        u32 Ab[12] = {A0.x, A0.y, A0.z, A0.w,
                      A1.x, A1.y, A1.z, A1.w,
                      A2.x, A2.y, A2.z, A2.w};
#pragma unroll
        for (int ks = 0; ks < 24; ++ks) {
            u32 pair = Ab[ks >> 1];
            u32 m = (ks & 1) ? (pair >> 16) : (pair & 0xFFFFu);
            afr[ks][0] = (int)(((m         & 0xFu) * 0x00204081u) & 0x01010101u);
            afr[ks][1] = (int)((((m >> 4)  & 0xFu) * 0x00204081u) & 0x01010101u);
            afr[ks][2] = (int)((((m >> 8)  & 0xFu) * 0x00204081u) & 0x01010101u);
            afr[ks][3] = (int)((((m >> 12)       ) * 0x00204081u) & 0x01010101u);
        }
    }

    int whoff[16];
#pragma unroll
    for (int g = 0; g < 16; ++g) {
        int er = (w << 5) + (g & 3) + ((g >> 2) << 3) + (hi << 2);
        whoff[g] = bmeta[er] << 10;             // bucket * 1024
    }

    const float sc = amax[0] * (1.0f / 127.0f);
    float rs[16];
#pragma unroll
    for (int g = 0; g < 16; ++g) rs[g] = 0.0f;

#define COMPUTE(buf, h_)                                                    \
    {                                                                       \
        const signed char* bb = (const signed char*)(buf)                   \
                                + (cl << 5) + (hi << 4);                    \
        _Pragma("unroll")                                                   \
        for (int kc = 0; kc < 12; ++kc) {                                   \
            int ks = (h_) * 12 + kc;                                        \
            i32x4 b0 = *(const i32x4*)(bb + (kc << 10));                    \
            i32x4 b1 = *(const i32x4*)(bb + 12288 + (kc << 10));            \
            acc0 = __builtin_amdgcn_mfma_i32_32x32x32_i8(afr[ks], b0, acc0, 0, 0, 0); \
            acc1 = __builtin_amdgcn_mfma_i32_32x32x32_i8(afr[ks], b1, acc1, 0, 0, 0); \
        }                                                                   \
    }

    // ---- main loop: 16 chunks x (2 K-half stages), 2 barriers/chunk -----
    for (int c = 0; c < 16; ++c) {
        i32x16 acc0 = {0,0,0,0,0,0,0,0,0,0,0,0,0,0,0,0};
        i32x16 acc1 = {0,0,0,0,0,0,0,0,0,0,0,0,0,0,0,0};

        // stage (c, half 1) into bufs[1]; compute (c, half 0) from bufs[0]
        STAGE(bufs[1], c, 1)
        COMPUTE(bufs[0], 0)
        __syncthreads();

        // stage (c+1, half 0) into bufs[0]; compute (c, half 1) from bufs[1]
        if (c < 15) STAGE(bufs[0], c + 1, 0)
        COMPUTE(bufs[1], 1)

        // fused epilogue (regs + L1-hot globals; covers the stage latency)
        const int col0 = (c << 6) + cl;
        const float bi0 = b_in[col0], bi1 = b_in[col0 + 32];
#pragma unroll
        for (int g = 0; g < 16; ++g) {
            float h0 = fminf(fmaxf(fmaf((float)acc0[g], sc, bi0), 0.f), 1.f);
            float h1 = fminf(fmaxf(fmaf((float)acc1[g], sc, bi1), 0.f), 1.f);
            rs[g] = fmaf(h0, W_h[whoff[g] + col0], rs[g]);
            rs[g] = fmaf(h1, W_h[whoff[g] + col0 + 32], rs[g]);
        }
        __syncthreads();
    }
#undef COMPUTE
#undef STAGE

    // ---- reduce over 32 col-lanes, write --------------------------------
#pragma unroll
    for (int g = 0; g < 16; ++g) {
#pragma unroll
        for (int d = 1; d < 32; d <<= 1) rs[g] += __shfl_xor(rs[g], d);
    }
    if (cl == 0) {
#pragma unroll
        for (int g = 0; g < 16; ++g) {
            int er = (w << 5) + (g & 3) + ((g >> 2) << 3) + (hi << 2);
            out[row0 + er] = rs[g] + pmeta[er] + b_h[whoff[g] >> 10];
        }
    }
}

extern "C" void kernel_launch(void* const* d_in, const int* in_sizes, int n_in,
                              void* d_out, int out_size, void* d_ws, size_t ws_size,
                              hipStream_t stream) {
    const float* x      = (const float*)d_in[0];
    const float* W_in   = (const float*)d_in[1];
    const float* b_in   = (const float*)d_in[2];
    const float* W_h    = (const float*)d_in[3];
    const float* b_h    = (const float*)d_in[4];
    const float* W_psqt = (const float*)d_in[5];
    float* out = (float*)d_out;

    float* amax = (float*)d_ws;
    float* part = (float*)((char*)d_ws + 64);
    signed char* Wq2 = (signed char*)d_ws + WQ_OFF;     // 768 KB

    amax_stage1<<<256, 256, 0, stream>>>(W_in, part);
    amax_stage2<<<1, 256, 0, stream>>>(part, amax);
    quant_k<<<1024, 192, 0, stream>>>(W_in, amax, (u32*)Wq2);

    int B = out_size;                   // 65536
    nnue_fwd<<<B / 128, 256, 0, stream>>>(x, Wq2, amax, b_in, W_h, b_h,
                                          W_psqt, out);
}